// Round 1
// baseline (265.770 us; speedup 1.0000x reference)
//
#include <hip/hip_runtime.h>
#include <math.h>

#define BB 4
#define NN 4096
#define MP 2048

// ---------------------------------------------------------------- min kernel
// Fused: rowmin (pred vs gt), colmin (gt vs pred), covmin (partial vs pred).
// Grid: 256 + 256 + 128 = 640 blocks x 256 threads.
// Each block: one batch, 256 queries, one 1024-candidate chunk (LDS staged).
// Result combined across chunks via atomicMin on float-as-uint (values >= 0).
__global__ __launch_bounds__(256) void kmin(const float* __restrict__ pred,
                                            const float* __restrict__ gt,
                                            const float* __restrict__ partial,
                                            unsigned* __restrict__ wrow,
                                            unsigned* __restrict__ wcol,
                                            unsigned* __restrict__ wcov) {
    __shared__ float cx[1024], cy[1024], cz[1024], cb[1024];
    int bid = blockIdx.x;
    const float* qptr; const float* cptr; unsigned* outp;
    int b, qb, ch, qn;
    if (bid < 256) {                       // pred -> gt
        b = bid >> 6; int r = bid & 63; qb = r >> 2; ch = r & 3;
        qptr = pred; cptr = gt; outp = wrow; qn = NN;
    } else if (bid < 512) {                // gt -> pred
        int l = bid - 256; b = l >> 6; int r = l & 63; qb = r >> 2; ch = r & 3;
        qptr = gt; cptr = pred; outp = wcol; qn = NN;
    } else {                               // partial -> pred
        int l = bid - 512; b = l >> 5; int r = l & 31; qb = r >> 2; ch = r & 3;
        qptr = partial; cptr = pred; outp = wcov; qn = MP;
    }
    // stage 1024 candidates (candidate sets are always 4096/batch)
    for (int t = threadIdx.x; t < 1024; t += 256) {
        int j = ch * 1024 + t;
        const float* p = cptr + ((size_t)b * NN + j) * 3;
        float x = p[0], y = p[1], z = p[2];
        cx[t] = x; cy[t] = y; cz[t] = z;
        cb[t] = fmaf(z, z, fmaf(y, y, x * x));
    }
    __syncthreads();
    int i = qb * 256 + threadIdx.x;
    const float* q = qptr + ((size_t)b * qn + i) * 3;
    float qx = q[0], qy = q[1], qz = q[2];
    float qq = fmaf(qz, qz, fmaf(qy, qy, qx * qx));
    float m = 1e30f;
#pragma unroll 8
    for (int jj = 0; jj < 1024; ++jj) {
        float dot = fmaf(qz, cz[jj], fmaf(qy, cy[jj], qx * cx[jj]));
        float sq  = fmaf(-2.f, dot, qq + cb[jj]);
        m = fminf(m, sq);
    }
    m = fmaxf(m, 0.f);
    atomicMin(outp + (size_t)b * qn + i, __float_as_uint(m));
}

// ---------------------------------------------------------------- knn kernel
// Per-thread sorted top-16 over a 1024-candidate chunk of pred (same batch).
// Key = (bits(sq) & ~0xFFF) | global_idx  (12-bit idx in low mantissa bits;
// unsigned order == float order for non-negative floats; lower idx wins ties,
// matching jax.lax.top_k).
__global__ __launch_bounds__(256) void kknn(const float* __restrict__ pred,
                                            unsigned* __restrict__ keys_out) {
    __shared__ float cx[1024], cy[1024], cz[1024], cb[1024];
    int bid = blockIdx.x;
    int b = bid >> 6; int r = bid & 63; int qb = r >> 2; int ch = r & 3;
    for (int t = threadIdx.x; t < 1024; t += 256) {
        int j = ch * 1024 + t;
        const float* p = pred + ((size_t)b * NN + j) * 3;
        float x = p[0], y = p[1], z = p[2];
        cx[t] = x; cy[t] = y; cz[t] = z;
        cb[t] = fmaf(z, z, fmaf(y, y, x * x));
    }
    __syncthreads();
    int i = qb * 256 + threadIdx.x;
    const float* q = pred + ((size_t)b * NN + i) * 3;
    float qx = q[0], qy = q[1], qz = q[2];
    float qq = fmaf(qz, qz, fmaf(qy, qy, qx * qx));
    unsigned keys[16];
#pragma unroll
    for (int k = 0; k < 16; ++k) keys[k] = 0xFFFFFFFFu;
    unsigned jbase = (unsigned)(ch * 1024);
    for (int jj = 0; jj < 1024; ++jj) {
        float dot = fmaf(qz, cz[jj], fmaf(qy, cy[jj], qx * cx[jj]));
        float sq  = fmaf(-2.f, dot, qq + cb[jj]);
        sq = fmaxf(sq, 0.f);
        unsigned key = (__float_as_uint(sq) & 0xFFFFF000u) | (jbase + (unsigned)jj);
        if (key < keys[15]) {
            // sorted insert via clamp identity; all reads are pre-update values
#pragma unroll
            for (int k = 15; k >= 1; --k)
                keys[k] = min(max(key, keys[k - 1]), keys[k]);
            keys[0] = min(key, keys[0]);
        }
    }
    size_t base = (((size_t)b * NN + i) * 4 + ch) * 16;
#pragma unroll
    for (int k = 0; k < 16; ++k) keys_out[base + k] = keys[k];
}

// -------------------------------------------------------------- merge kernel
// Merge 4x16 chunk lists -> global top-16; compute repulsion (ranks 1..8,
// exact recompute) and smoothness variance (ranks 0..15). 64 blocks x 256.
__global__ __launch_bounds__(256) void kmerge(const float* __restrict__ pred,
                                              const unsigned* __restrict__ keys_in,
                                              float* __restrict__ partials) {
    __shared__ float px[NN], py[NN], pz[NN];
    __shared__ float red[256];
    int bid = blockIdx.x;
    int b = bid >> 4; int qb = bid & 15;
    for (int t = threadIdx.x; t < NN; t += 256) {
        const float* p = pred + ((size_t)b * NN + t) * 3;
        px[t] = p[0]; py[t] = p[1]; pz[t] = p[2];
    }
    __syncthreads();
    int i = qb * 256 + threadIdx.x;
    float qx = px[i], qy = py[i], qz = pz[i];
    float qq = fmaf(qz, qz, fmaf(qy, qy, qx * qx));
    unsigned keys[16];
#pragma unroll
    for (int k = 0; k < 16; ++k) keys[k] = 0xFFFFFFFFu;
    size_t base = ((size_t)b * NN + i) * 64;
    for (int c = 0; c < 64; ++c) {
        unsigned key = keys_in[base + c];
        if (key < keys[15]) {
#pragma unroll
            for (int k = 15; k >= 1; --k)
                keys[k] = min(max(key, keys[k - 1]), keys[k]);
            keys[0] = min(key, keys[0]);
        }
    }
    // repulsion: ranks 1..8 (rank 0 is the zero-distance self/duplicate)
    float rep = 0.f;
#pragma unroll
    for (int r = 1; r <= 8; ++r) {
        int idx = (int)(keys[r] & 0xFFFu);
        float x = px[idx], y = py[idx], z = pz[idx];
        float bb2 = fmaf(z, z, fmaf(y, y, x * x));
        float dot = fmaf(qz, z, fmaf(qy, y, qx * x));
        float sq  = fmaf(-2.f, dot, qq + bb2);
        sq = fmaxf(sq, 0.f);
        float d = (sq > 1e-12f) ? sqrtf(sq) : 0.f;
        rep += fmaxf(0.005f - d, 0.f);
    }
    // smoothness: two-pass variance over the 16 nearest (incl. self)
    float sx = 0.f, sy = 0.f, sz = 0.f;
#pragma unroll
    for (int r = 0; r < 16; ++r) {
        int idx = (int)(keys[r] & 0xFFFu);
        sx += px[idx]; sy += py[idx]; sz += pz[idx];
    }
    float mx = sx * (1.f / 16.f), my = sy * (1.f / 16.f), mz = sz * (1.f / 16.f);
    float var = 0.f;
#pragma unroll
    for (int r = 0; r < 16; ++r) {
        int idx = (int)(keys[r] & 0xFFFu);
        float dx = px[idx] - mx, dy = py[idx] - my, dz = pz[idx] - mz;
        var += dx * dx + dy * dy + dz * dz;
    }
    var *= (1.f / 47.f);
    // deterministic block tree reductions
    red[threadIdx.x] = rep; __syncthreads();
    for (int s = 128; s > 0; s >>= 1) {
        if (threadIdx.x < s) red[threadIdx.x] += red[threadIdx.x + s];
        __syncthreads();
    }
    float rsum = red[0]; __syncthreads();
    red[threadIdx.x] = var; __syncthreads();
    for (int s = 128; s > 0; s >>= 1) {
        if (threadIdx.x < s) red[threadIdx.x] += red[threadIdx.x + s];
        __syncthreads();
    }
    if (threadIdx.x == 0) {
        partials[bid * 2 + 0] = rsum;
        partials[bid * 2 + 1] = red[0];
    }
}

// -------------------------------------------------------------- final kernel
__device__ __forceinline__ float block_reduce(float v, float* red) {
    int t = threadIdx.x;
    red[t] = v; __syncthreads();
    for (int s = 512; s > 0; s >>= 1) {
        if (t < s) red[t] += red[t + s];
        __syncthreads();
    }
    float r = red[0]; __syncthreads();
    return r;
}

__global__ __launch_bounds__(1024) void kfinal(const unsigned* __restrict__ wrow,
                                               const unsigned* __restrict__ wcol,
                                               const unsigned* __restrict__ wcov,
                                               const float* __restrict__ partials,
                                               const float* __restrict__ partialpts,
                                               float* __restrict__ out) {
    __shared__ float red[1024];
    int t = threadIdx.x;
    float srow = 0.f;
    for (int idx = t; idx < BB * NN; idx += 1024) {
        float sq = __uint_as_float(wrow[idx]);
        srow += (sq > 1e-12f) ? sqrtf(sq) : 0.f;
    }
    float scol = 0.f;
    for (int idx = t; idx < BB * NN; idx += 1024) {
        float sq = __uint_as_float(wcol[idx]);
        scol += (sq > 1e-12f) ? sqrtf(sq) : 0.f;
    }
    float covs0, covs1, covs2, covs3, covc0, covc1, covc2, covc3;
    {
        float s[4], c[4];
#pragma unroll
        for (int b2 = 0; b2 < 4; ++b2) {
            float ss = 0.f, cc = 0.f;
            for (int j = t; j < MP; j += 1024) {
                const float* p = partialpts + ((size_t)b2 * MP + j) * 3;
                float am = fabsf(p[0]) + fabsf(p[1]) + fabsf(p[2]);
                float m = (am > 1e-6f) ? 1.f : 0.f;
                float sq = __uint_as_float(wcov[b2 * MP + j]);
                float d = (sq > 1e-12f) ? sqrtf(sq) : 0.f;
                ss += d * m; cc += m;
            }
            s[b2] = ss; c[b2] = cc;
        }
        covs0 = s[0]; covs1 = s[1]; covs2 = s[2]; covs3 = s[3];
        covc0 = c[0]; covc1 = c[1]; covc2 = c[2]; covc3 = c[3];
    }
    float pr = 0.f, pv = 0.f;
    if (t < 64) { pr = partials[t * 2]; pv = partials[t * 2 + 1]; }

    float SROW = block_reduce(srow, red);
    float SCOL = block_reduce(scol, red);
    float CS0 = block_reduce(covs0, red);
    float CS1 = block_reduce(covs1, red);
    float CS2 = block_reduce(covs2, red);
    float CS3 = block_reduce(covs3, red);
    float CC0 = block_reduce(covc0, red);
    float CC1 = block_reduce(covc1, red);
    float CC2 = block_reduce(covc2, red);
    float CC3 = block_reduce(covc3, red);
    float PR = block_reduce(pr, red);
    float PV = block_reduce(pv, red);

    if (t == 0) {
        const float inv_bn = 1.f / (float)(BB * NN);
        float chamfer = (SROW + SCOL) * inv_bn;                  // W_CHAMFER = 1
        float repulsion = PR * inv_bn * (1.f / 8.f) * 0.1f;      // mean over B*N*8
        float per0 = (CC0 > 0.f) ? CS0 / fmaxf(CC0, 1.f) : 0.f;
        float per1 = (CC1 > 0.f) ? CS1 / fmaxf(CC1, 1.f) : 0.f;
        float per2 = (CC2 > 0.f) ? CS2 / fmaxf(CC2, 1.f) : 0.f;
        float per3 = (CC3 > 0.f) ? CS3 / fmaxf(CC3, 1.f) : 0.f;
        float coverage = (per0 + per1 + per2 + per3) * 0.25f * 0.2f;
        float smooth = PV * inv_bn * 0.05f;
        out[0] = chamfer;
        out[1] = repulsion;
        out[2] = coverage;
        out[3] = smooth;
        out[4] = chamfer + repulsion + coverage + smooth;
    }
}

extern "C" void kernel_launch(void* const* d_in, const int* in_sizes, int n_in,
                              void* d_out, int out_size, void* d_ws, size_t ws_size,
                              hipStream_t stream) {
    const float* pred    = (const float*)d_in[0];
    const float* gt      = (const float*)d_in[1];
    const float* partial = (const float*)d_in[2];
    float* out = (float*)d_out;

    unsigned* wrow  = (unsigned*)d_ws;                    // B*N   = 16384
    unsigned* wcol  = wrow + (size_t)BB * NN;             // B*N   = 16384
    unsigned* wcov  = wcol + (size_t)BB * NN;             // B*MP  = 8192
    unsigned* wkeys = wcov + (size_t)BB * MP;             // B*N*64 = 1048576
    float* partials = (float*)(wkeys + (size_t)BB * NN * 64); // 128

    // init min arrays to uint-max (== +inf for the bitwise-min trick)
    hipMemsetAsync(wrow, 0xFF, (size_t)(BB * NN * 2 + BB * MP) * sizeof(unsigned), stream);

    kmin  <<<640, 256, 0, stream>>>(pred, gt, partial, wrow, wcol, wcov);
    kknn  <<<256, 256, 0, stream>>>(pred, wkeys);
    kmerge<<< 64, 256, 0, stream>>>(pred, wkeys, partials);
    kfinal<<<  1, 1024, 0, stream>>>(wrow, wcol, wcov, partials, partial, out);
}

// Round 2
// 160.432 us; speedup vs baseline: 1.6566x; 1.6566x over previous
//
#include <hip/hip_runtime.h>
#include <math.h>

#define BB 4
#define NN 4096
#define MP 2048

// Sorted top-16 insert via clamp identity (all static indices -> VGPRs).
#define INSERT16(keys, key)                                   \
    do {                                                      \
        if ((key) < keys[15]) {                               \
            _Pragma("unroll")                                 \
            for (int _k = 15; _k >= 1; --_k)                  \
                keys[_k] = min(max((key), keys[_k - 1]), keys[_k]); \
            keys[0] = min((key), keys[0]);                    \
        }                                                     \
    } while (0)

// ------------------------------------------------------------ fused kernel
// Regions (one grid, 1152 blocks x 256):
//   A [0,256):    pred -> gt   min   (512 q/block, 2 q/thread, 8 chunks x512)
//   B [256,512):  gt   -> pred min
//   C [512,640):  partial -> pred min (2048 queries/batch)
//   D [640,1152): pred -> pred top-16 per 512-candidate chunk (1 q/thread)
__global__ __launch_bounds__(256) void kfused(const float* __restrict__ pred,
                                              const float* __restrict__ gt,
                                              const float* __restrict__ partial,
                                              unsigned* __restrict__ wrow,
                                              unsigned* __restrict__ wcol,
                                              unsigned* __restrict__ wcov,
                                              unsigned* __restrict__ wkeys) {
    __shared__ float4 cand[512];
    int bid = blockIdx.x;

    if (bid < 640) {
        // ---------------- min path ----------------
        const float* qptr; const float* cptr; unsigned* outp;
        int b, qb, ch, qn;
        if (bid < 256) {
            b = bid >> 6; int r = bid & 63; qb = r >> 3; ch = r & 7;
            qptr = pred; cptr = gt; outp = wrow; qn = NN;
        } else if (bid < 512) {
            int l = bid - 256; b = l >> 6; int r = l & 63; qb = r >> 3; ch = r & 7;
            qptr = gt; cptr = pred; outp = wcol; qn = NN;
        } else {
            int l = bid - 512; b = l >> 5; int r = l & 31; qb = r >> 3; ch = r & 7;
            qptr = partial; cptr = pred; outp = wcov; qn = MP;
        }
        for (int t = threadIdx.x; t < 512; t += 256) {
            int j = ch * 512 + t;
            const float* p = cptr + ((size_t)b * NN + j) * 3;
            float x = p[0], y = p[1], z = p[2];
            cand[t] = make_float4(x, y, z, fmaf(z, z, fmaf(y, y, x * x)));
        }
        __syncthreads();
        int i0 = qb * 512 + threadIdx.x;
        int i1 = i0 + 256;
        const float* q0 = qptr + ((size_t)b * qn + i0) * 3;
        const float* q1 = qptr + ((size_t)b * qn + i1) * 3;
        float q0x = q0[0], q0y = q0[1], q0z = q0[2];
        float q1x = q1[0], q1y = q1[1], q1z = q1[2];
        float q0q = fmaf(q0z, q0z, fmaf(q0y, q0y, q0x * q0x));
        float q1q = fmaf(q1z, q1z, fmaf(q1y, q1y, q1x * q1x));
        float m0 = 1e30f, m1 = 1e30f;
#pragma unroll 4
        for (int jj = 0; jj < 512; ++jj) {
            float4 c = cand[jj];
            float d0 = fmaf(q0z, c.z, fmaf(q0y, c.y, q0x * c.x));
            float d1 = fmaf(q1z, c.z, fmaf(q1y, c.y, q1x * c.x));
            m0 = fminf(m0, fmaf(-2.f, d0, q0q + c.w));
            m1 = fminf(m1, fmaf(-2.f, d1, q1q + c.w));
        }
        atomicMin(outp + (size_t)b * qn + i0, __float_as_uint(fmaxf(m0, 0.f)));
        atomicMin(outp + (size_t)b * qn + i1, __float_as_uint(fmaxf(m1, 0.f)));
    } else {
        // ---------------- knn path ----------------
        int l = bid - 640;
        int b = l >> 7; int r = l & 127; int qb = r >> 3; int ch = r & 7;
        for (int t = threadIdx.x; t < 512; t += 256) {
            int j = ch * 512 + t;
            const float* p = pred + ((size_t)b * NN + j) * 3;
            float x = p[0], y = p[1], z = p[2];
            cand[t] = make_float4(x, y, z, fmaf(z, z, fmaf(y, y, x * x)));
        }
        __syncthreads();
        int i = qb * 256 + threadIdx.x;
        const float* q = pred + ((size_t)b * NN + i) * 3;
        float qx = q[0], qy = q[1], qz = q[2];
        float qq = fmaf(qz, qz, fmaf(qy, qy, qx * qx));
        unsigned keys[16];
#pragma unroll
        for (int k = 0; k < 16; ++k) keys[k] = 0xFFFFFFFFu;
        unsigned jbase = (unsigned)(ch * 512);
        for (int jj = 0; jj < 512; ++jj) {
            float4 c = cand[jj];
            float dot = fmaf(qz, c.z, fmaf(qy, c.y, qx * c.x));
            float sq  = fmaxf(fmaf(-2.f, dot, qq + c.w), 0.f);
            unsigned key = (__float_as_uint(sq) & 0xFFFFF000u) | (jbase + (unsigned)jj);
            INSERT16(keys, key);
        }
        size_t base = (((size_t)b * NN + i) * 8 + ch) * 16;
#pragma unroll
        for (int k = 0; k < 16; ++k) wkeys[base + k] = keys[k];
    }
}

// -------------------------------------------------------------- merge kernel
// Merge 8x16 chunk lists -> global top-16; repulsion (ranks 1..8, exact
// recompute) and smoothness variance (ranks 0..15). 64 blocks x 256.
__global__ __launch_bounds__(256) void kmerge(const float* __restrict__ pred,
                                              const unsigned* __restrict__ keys_in,
                                              float* __restrict__ partials) {
    __shared__ float px[NN], py[NN], pz[NN];
    __shared__ float red[256];
    int bid = blockIdx.x;
    int b = bid >> 4; int qb = bid & 15;
    for (int t = threadIdx.x; t < NN; t += 256) {
        const float* p = pred + ((size_t)b * NN + t) * 3;
        px[t] = p[0]; py[t] = p[1]; pz[t] = p[2];
    }
    __syncthreads();
    int i = qb * 256 + threadIdx.x;
    float qx = px[i], qy = py[i], qz = pz[i];
    float qq = fmaf(qz, qz, fmaf(qy, qy, qx * qx));
    unsigned keys[16];
#pragma unroll
    for (int k = 0; k < 16; ++k) keys[k] = 0xFFFFFFFFu;
    size_t base = ((size_t)b * NN + i) * 128;
    for (int c = 0; c < 128; ++c) {
        unsigned key = keys_in[base + c];
        INSERT16(keys, key);
    }
    float rep = 0.f;
#pragma unroll
    for (int r = 1; r <= 8; ++r) {
        int idx = (int)(keys[r] & 0xFFFu);
        float x = px[idx], y = py[idx], z = pz[idx];
        float bb2 = fmaf(z, z, fmaf(y, y, x * x));
        float dot = fmaf(qz, z, fmaf(qy, y, qx * x));
        float sq  = fmaxf(fmaf(-2.f, dot, qq + bb2), 0.f);
        float d = (sq > 1e-12f) ? sqrtf(sq) : 0.f;
        rep += fmaxf(0.005f - d, 0.f);
    }
    float sx = 0.f, sy = 0.f, sz = 0.f;
#pragma unroll
    for (int r = 0; r < 16; ++r) {
        int idx = (int)(keys[r] & 0xFFFu);
        sx += px[idx]; sy += py[idx]; sz += pz[idx];
    }
    float mx = sx * (1.f / 16.f), my = sy * (1.f / 16.f), mz = sz * (1.f / 16.f);
    float var = 0.f;
#pragma unroll
    for (int r = 0; r < 16; ++r) {
        int idx = (int)(keys[r] & 0xFFFu);
        float dx = px[idx] - mx, dy = py[idx] - my, dz = pz[idx] - mz;
        var += dx * dx + dy * dy + dz * dz;
    }
    var *= (1.f / 47.f);
    red[threadIdx.x] = rep; __syncthreads();
    for (int s = 128; s > 0; s >>= 1) {
        if (threadIdx.x < s) red[threadIdx.x] += red[threadIdx.x + s];
        __syncthreads();
    }
    float rsum = red[0]; __syncthreads();
    red[threadIdx.x] = var; __syncthreads();
    for (int s = 128; s > 0; s >>= 1) {
        if (threadIdx.x < s) red[threadIdx.x] += red[threadIdx.x + s];
        __syncthreads();
    }
    if (threadIdx.x == 0) {
        partials[bid * 2 + 0] = rsum;
        partials[bid * 2 + 1] = red[0];
    }
}

// -------------------------------------------------------------- final kernel
__device__ __forceinline__ float block_reduce(float v, float* red) {
    int t = threadIdx.x;
    red[t] = v; __syncthreads();
    for (int s = 512; s > 0; s >>= 1) {
        if (t < s) red[t] += red[t + s];
        __syncthreads();
    }
    float r = red[0]; __syncthreads();
    return r;
}

__global__ __launch_bounds__(1024) void kfinal(const unsigned* __restrict__ wrow,
                                               const unsigned* __restrict__ wcol,
                                               const unsigned* __restrict__ wcov,
                                               const float* __restrict__ partials,
                                               const float* __restrict__ partialpts,
                                               float* __restrict__ out) {
    __shared__ float red[1024];
    int t = threadIdx.x;
    float srow = 0.f;
    for (int idx = t; idx < BB * NN; idx += 1024) {
        float sq = __uint_as_float(wrow[idx]);
        srow += (sq > 1e-12f) ? sqrtf(sq) : 0.f;
    }
    float scol = 0.f;
    for (int idx = t; idx < BB * NN; idx += 1024) {
        float sq = __uint_as_float(wcol[idx]);
        scol += (sq > 1e-12f) ? sqrtf(sq) : 0.f;
    }
    float cs[4], cc[4];
#pragma unroll
    for (int b2 = 0; b2 < 4; ++b2) {
        float ss = 0.f, ccv = 0.f;
        for (int j = t; j < MP; j += 1024) {
            const float* p = partialpts + ((size_t)b2 * MP + j) * 3;
            float am = fabsf(p[0]) + fabsf(p[1]) + fabsf(p[2]);
            float m = (am > 1e-6f) ? 1.f : 0.f;
            float sq = __uint_as_float(wcov[b2 * MP + j]);
            float d = (sq > 1e-12f) ? sqrtf(sq) : 0.f;
            ss += d * m; ccv += m;
        }
        cs[b2] = ss; cc[b2] = ccv;
    }
    float pr = 0.f, pv = 0.f;
    if (t < 64) { pr = partials[t * 2]; pv = partials[t * 2 + 1]; }

    float SROW = block_reduce(srow, red);
    float SCOL = block_reduce(scol, red);
    float CS0 = block_reduce(cs[0], red);
    float CS1 = block_reduce(cs[1], red);
    float CS2 = block_reduce(cs[2], red);
    float CS3 = block_reduce(cs[3], red);
    float CC0 = block_reduce(cc[0], red);
    float CC1 = block_reduce(cc[1], red);
    float CC2 = block_reduce(cc[2], red);
    float CC3 = block_reduce(cc[3], red);
    float PR = block_reduce(pr, red);
    float PV = block_reduce(pv, red);

    if (t == 0) {
        const float inv_bn = 1.f / (float)(BB * NN);
        float chamfer = (SROW + SCOL) * inv_bn;
        float repulsion = PR * inv_bn * (1.f / 8.f) * 0.1f;
        float per0 = (CC0 > 0.f) ? CS0 / fmaxf(CC0, 1.f) : 0.f;
        float per1 = (CC1 > 0.f) ? CS1 / fmaxf(CC1, 1.f) : 0.f;
        float per2 = (CC2 > 0.f) ? CS2 / fmaxf(CC2, 1.f) : 0.f;
        float per3 = (CC3 > 0.f) ? CS3 / fmaxf(CC3, 1.f) : 0.f;
        float coverage = (per0 + per1 + per2 + per3) * 0.25f * 0.2f;
        float smooth = PV * inv_bn * 0.05f;
        out[0] = chamfer;
        out[1] = repulsion;
        out[2] = coverage;
        out[3] = smooth;
        out[4] = chamfer + repulsion + coverage + smooth;
    }
}

extern "C" void kernel_launch(void* const* d_in, const int* in_sizes, int n_in,
                              void* d_out, int out_size, void* d_ws, size_t ws_size,
                              hipStream_t stream) {
    const float* pred    = (const float*)d_in[0];
    const float* gt      = (const float*)d_in[1];
    const float* partial = (const float*)d_in[2];
    float* out = (float*)d_out;

    unsigned* wrow  = (unsigned*)d_ws;                        // B*N      = 16384
    unsigned* wcol  = wrow + (size_t)BB * NN;                 // B*N      = 16384
    unsigned* wcov  = wcol + (size_t)BB * NN;                 // B*MP     = 8192
    unsigned* wkeys = wcov + (size_t)BB * MP;                 // B*N*8*16 = 2097152
    float* partials = (float*)(wkeys + (size_t)BB * NN * 128); // 128

    hipMemsetAsync(wrow, 0xFF, (size_t)(BB * NN * 2 + BB * MP) * sizeof(unsigned), stream);

    kfused<<<1152, 256, 0, stream>>>(pred, gt, partial, wrow, wcol, wcov, wkeys);
    kmerge<<<  64, 256, 0, stream>>>(pred, wkeys, partials);
    kfinal<<<   1, 1024, 0, stream>>>(wrow, wcol, wcov, partials, partial, out);
}

// Round 3
// 154.456 us; speedup vs baseline: 1.7207x; 1.0387x over previous
//
#include <hip/hip_runtime.h>
#include <math.h>

#define BB 4
#define NN 4096
#define MP 2048

// Sorted top-16 insert via clamp identity (all static indices -> VGPRs).
// Reads are all pre-update values, so the 16 slot updates are independent (ILP).
#define INSERT16(keys, key)                                   \
    do {                                                      \
        if ((key) < keys[15]) {                               \
            _Pragma("unroll")                                 \
            for (int _k = 15; _k >= 1; --_k)                  \
                keys[_k] = min(max((key), keys[_k - 1]), keys[_k]); \
            keys[0] = min((key), keys[0]);                    \
        }                                                     \
    } while (0)

// ------------------------------------------------------------ fused kernel
// Template over NCH = number of candidate chunks (4096/NCH candidates each).
// Regions (bid ranges), NCH=16 -> 2304 blocks total:
//   rowmin [0,          4*8*NCH):   pred -> gt    (512 q/block, 2 q/thread)
//   colmin [.., +4*8*NCH):          gt   -> pred
//   cov    [.., +4*4*NCH):          partial -> pred
//   knn    [.., +4*16*NCH):         pred -> pred top-16 per chunk (1 q/thread)
template <int NCH>
__global__ __launch_bounds__(256) void kfused(const float* __restrict__ pred,
                                              const float* __restrict__ gt,
                                              const float* __restrict__ partial,
                                              unsigned* __restrict__ wrow,
                                              unsigned* __restrict__ wcol,
                                              unsigned* __restrict__ wcov,
                                              unsigned* __restrict__ wkeys) {
    constexpr int CAND = NN / NCH;
    constexpr int R0 = 4 * 8 * NCH;
    constexpr int R1 = R0 + 4 * 8 * NCH;
    constexpr int R2 = R1 + 4 * 4 * NCH;
    __shared__ float4 cand[CAND];
    int bid = blockIdx.x;

    if (bid < R2) {
        // ---------------- min path ----------------
        const float* qptr; const float* cptr; unsigned* outp;
        int b, qb, ch, qn;
        if (bid < R0) {
            b = bid / (8 * NCH); int r = bid % (8 * NCH); qb = r / NCH; ch = r % NCH;
            qptr = pred; cptr = gt; outp = wrow; qn = NN;
        } else if (bid < R1) {
            int l = bid - R0;
            b = l / (8 * NCH); int r = l % (8 * NCH); qb = r / NCH; ch = r % NCH;
            qptr = gt; cptr = pred; outp = wcol; qn = NN;
        } else {
            int l = bid - R1;
            b = l / (4 * NCH); int r = l % (4 * NCH); qb = r / NCH; ch = r % NCH;
            qptr = partial; cptr = pred; outp = wcov; qn = MP;
        }
        for (int t = threadIdx.x; t < CAND; t += 256) {
            int j = ch * CAND + t;
            const float* p = cptr + ((size_t)b * NN + j) * 3;
            float x = p[0], y = p[1], z = p[2];
            cand[t] = make_float4(x, y, z, fmaf(z, z, fmaf(y, y, x * x)));
        }
        __syncthreads();
        int i0 = qb * 512 + threadIdx.x;
        int i1 = i0 + 256;
        const float* q0 = qptr + ((size_t)b * qn + i0) * 3;
        const float* q1 = qptr + ((size_t)b * qn + i1) * 3;
        float q0x = q0[0], q0y = q0[1], q0z = q0[2];
        float q1x = q1[0], q1y = q1[1], q1z = q1[2];
        float q0q = fmaf(q0z, q0z, fmaf(q0y, q0y, q0x * q0x));
        float q1q = fmaf(q1z, q1z, fmaf(q1y, q1y, q1x * q1x));
        float m0 = 1e30f, m1 = 1e30f;
#pragma unroll 4
        for (int jj = 0; jj < CAND; ++jj) {
            float4 c = cand[jj];
            float d0 = fmaf(q0z, c.z, fmaf(q0y, c.y, q0x * c.x));
            float d1 = fmaf(q1z, c.z, fmaf(q1y, c.y, q1x * c.x));
            m0 = fminf(m0, fmaf(-2.f, d0, q0q + c.w));
            m1 = fminf(m1, fmaf(-2.f, d1, q1q + c.w));
        }
        atomicMin(outp + (size_t)b * qn + i0, __float_as_uint(fmaxf(m0, 0.f)));
        atomicMin(outp + (size_t)b * qn + i1, __float_as_uint(fmaxf(m1, 0.f)));
    } else {
        // ---------------- knn path ----------------
        int l = bid - R2;
        int b = l / (16 * NCH); int r = l % (16 * NCH); int qb = r / NCH; int ch = r % NCH;
        for (int t = threadIdx.x; t < CAND; t += 256) {
            int j = ch * CAND + t;
            const float* p = pred + ((size_t)b * NN + j) * 3;
            float x = p[0], y = p[1], z = p[2];
            cand[t] = make_float4(x, y, z, fmaf(z, z, fmaf(y, y, x * x)));
        }
        __syncthreads();
        int i = qb * 256 + threadIdx.x;
        const float* q = pred + ((size_t)b * NN + i) * 3;
        float qx = q[0], qy = q[1], qz = q[2];
        float qq = fmaf(qz, qz, fmaf(qy, qy, qx * qx));
        unsigned keys[16];
#pragma unroll
        for (int k = 0; k < 16; ++k) keys[k] = 0xFFFFFFFFu;
        unsigned jbase = (unsigned)(ch * CAND);
#pragma unroll 4
        for (int jj = 0; jj < CAND; ++jj) {
            float4 c = cand[jj];
            float dot = fmaf(qz, c.z, fmaf(qy, c.y, qx * c.x));
            float sq  = fmaxf(fmaf(-2.f, dot, qq + c.w), 0.f);
            unsigned key = (__float_as_uint(sq) & 0xFFFFF000u) | (jbase + (unsigned)jj);
            INSERT16(keys, key);
        }
        size_t base = (((size_t)b * NN + i) * NCH + ch) * 16;
#pragma unroll
        for (int k = 0; k < 16; ++k) wkeys[base + k] = keys[k];
    }
}

// ------------------------------------------------------------ merge stage A
// Per query: merge 4 chunk lists (64 keys) -> one group list of 16.
// Blocks = (16384/256) * G, threads 256 (1 query each).
template <int NCH>
__global__ __launch_bounds__(256) void kmergeA(const unsigned* __restrict__ wkeys,
                                               unsigned* __restrict__ wkeys2) {
    constexpr int G = NCH / 4;
    int bid = blockIdx.x;
    int qblk = bid / G, g = bid % G;
    int q = qblk * 256 + threadIdx.x;
    unsigned keys[16];
#pragma unroll
    for (int k = 0; k < 16; ++k) keys[k] = 0xFFFFFFFFu;
    const unsigned* src = wkeys + ((size_t)q * NCH + g * 4) * 16;
    for (int c = 0; c < 64; ++c) {
        unsigned key = src[c];
        INSERT16(keys, key);
    }
    unsigned* dst = wkeys2 + ((size_t)q * G + g) * 16;
#pragma unroll
    for (int k = 0; k < 16; ++k) dst[k] = keys[k];
}

// ------------------------------------------------------------ merge stage B
// Merge G lists of 16 -> global top-16; gather neighbor coords from global
// (L2-resident), compute repulsion (ranks 1..8) + smoothness variance
// (ranks 0..15). 256 blocks x 64 threads (1 wave), wave-reduce partials.
template <int G>
__global__ __launch_bounds__(64) void kmergeB(const float* __restrict__ pred,
                                              const unsigned* __restrict__ wk,
                                              float* __restrict__ partials) {
    int q = blockIdx.x * 64 + threadIdx.x;   // [0, 16384)
    int b = q >> 12;
    int i = q & (NN - 1);
    unsigned keys[16];
#pragma unroll
    for (int k = 0; k < 16; ++k) keys[k] = 0xFFFFFFFFu;
    const unsigned* src = wk + (size_t)q * (G * 16);
    for (int c = 0; c < G * 16; ++c) {
        unsigned key = src[c];
        INSERT16(keys, key);
    }
    // own coords
    const float* qp = pred + ((size_t)b * NN + i) * 3;
    float qx = qp[0], qy = qp[1], qz = qp[2];
    float qq = fmaf(qz, qz, fmaf(qy, qy, qx * qx));
    // gather 16 neighbor coords (static-indexed arrays -> VGPRs)
    float cxv[16], cyv[16], czv[16];
#pragma unroll
    for (int r = 0; r < 16; ++r) {
        int idx = (int)(keys[r] & 0xFFFu);
        const float* p = pred + ((size_t)b * NN + idx) * 3;
        cxv[r] = p[0]; cyv[r] = p[1]; czv[r] = p[2];
    }
    // repulsion over ranks 1..8 (rank 0 = self, distance 0)
    float rep = 0.f;
#pragma unroll
    for (int r = 1; r <= 8; ++r) {
        float x = cxv[r], y = cyv[r], z = czv[r];
        float bb2 = fmaf(z, z, fmaf(y, y, x * x));
        float dot = fmaf(qz, z, fmaf(qy, y, qx * x));
        float sq  = fmaxf(fmaf(-2.f, dot, qq + bb2), 0.f);
        float d = (sq > 1e-12f) ? sqrtf(sq) : 0.f;
        rep += fmaxf(0.005f - d, 0.f);
    }
    // smoothness: two-pass variance over ranks 0..15
    float sx = 0.f, sy = 0.f, sz = 0.f;
#pragma unroll
    for (int r = 0; r < 16; ++r) { sx += cxv[r]; sy += cyv[r]; sz += czv[r]; }
    float mx = sx * (1.f / 16.f), my = sy * (1.f / 16.f), mz = sz * (1.f / 16.f);
    float var = 0.f;
#pragma unroll
    for (int r = 0; r < 16; ++r) {
        float dx = cxv[r] - mx, dy = cyv[r] - my, dz = czv[r] - mz;
        var += dx * dx + dy * dy + dz * dz;
    }
    var *= (1.f / 47.f);
    // wave reduce (64 lanes)
#pragma unroll
    for (int off = 32; off > 0; off >>= 1) {
        rep += __shfl_down(rep, off);
        var += __shfl_down(var, off);
    }
    if (threadIdx.x == 0) {
        partials[blockIdx.x * 2 + 0] = rep;
        partials[blockIdx.x * 2 + 1] = var;
    }
}

// -------------------------------------------------------------- final kernel
__device__ __forceinline__ float block_reduce(float v, float* red) {
    int t = threadIdx.x;
    red[t] = v; __syncthreads();
    for (int s = 512; s > 0; s >>= 1) {
        if (t < s) red[t] += red[t + s];
        __syncthreads();
    }
    float r = red[0]; __syncthreads();
    return r;
}

__global__ __launch_bounds__(1024) void kfinal(const unsigned* __restrict__ wrow,
                                               const unsigned* __restrict__ wcol,
                                               const unsigned* __restrict__ wcov,
                                               const float* __restrict__ partials,
                                               const float* __restrict__ partialpts,
                                               float* __restrict__ out) {
    __shared__ float red[1024];
    int t = threadIdx.x;
    float srow = 0.f;
    for (int idx = t; idx < BB * NN; idx += 1024) {
        float sq = __uint_as_float(wrow[idx]);
        srow += (sq > 1e-12f) ? sqrtf(sq) : 0.f;
    }
    float scol = 0.f;
    for (int idx = t; idx < BB * NN; idx += 1024) {
        float sq = __uint_as_float(wcol[idx]);
        scol += (sq > 1e-12f) ? sqrtf(sq) : 0.f;
    }
    float cs[4], cc[4];
#pragma unroll
    for (int b2 = 0; b2 < 4; ++b2) {
        float ss = 0.f, ccv = 0.f;
        for (int j = t; j < MP; j += 1024) {
            const float* p = partialpts + ((size_t)b2 * MP + j) * 3;
            float am = fabsf(p[0]) + fabsf(p[1]) + fabsf(p[2]);
            float m = (am > 1e-6f) ? 1.f : 0.f;
            float sq = __uint_as_float(wcov[b2 * MP + j]);
            float d = (sq > 1e-12f) ? sqrtf(sq) : 0.f;
            ss += d * m; ccv += m;
        }
        cs[b2] = ss; cc[b2] = ccv;
    }
    float pr = 0.f, pv = 0.f;
    if (t < 256) { pr = partials[t * 2]; pv = partials[t * 2 + 1]; }

    float SROW = block_reduce(srow, red);
    float SCOL = block_reduce(scol, red);
    float CS0 = block_reduce(cs[0], red);
    float CS1 = block_reduce(cs[1], red);
    float CS2 = block_reduce(cs[2], red);
    float CS3 = block_reduce(cs[3], red);
    float CC0 = block_reduce(cc[0], red);
    float CC1 = block_reduce(cc[1], red);
    float CC2 = block_reduce(cc[2], red);
    float CC3 = block_reduce(cc[3], red);
    float PR = block_reduce(pr, red);
    float PV = block_reduce(pv, red);

    if (t == 0) {
        const float inv_bn = 1.f / (float)(BB * NN);
        float chamfer = (SROW + SCOL) * inv_bn;
        float repulsion = PR * inv_bn * (1.f / 8.f) * 0.1f;
        float per0 = (CC0 > 0.f) ? CS0 / fmaxf(CC0, 1.f) : 0.f;
        float per1 = (CC1 > 0.f) ? CS1 / fmaxf(CC1, 1.f) : 0.f;
        float per2 = (CC2 > 0.f) ? CS2 / fmaxf(CC2, 1.f) : 0.f;
        float per3 = (CC3 > 0.f) ? CS3 / fmaxf(CC3, 1.f) : 0.f;
        float coverage = (per0 + per1 + per2 + per3) * 0.25f * 0.2f;
        float smooth = PV * inv_bn * 0.05f;
        out[0] = chamfer;
        out[1] = repulsion;
        out[2] = coverage;
        out[3] = smooth;
        out[4] = chamfer + repulsion + coverage + smooth;
    }
}

extern "C" void kernel_launch(void* const* d_in, const int* in_sizes, int n_in,
                              void* d_out, int out_size, void* d_ws, size_t ws_size,
                              hipStream_t stream) {
    const float* pred    = (const float*)d_in[0];
    const float* gt      = (const float*)d_in[1];
    const float* partial = (const float*)d_in[2];
    float* out = (float*)d_out;

    const size_t NQ = (size_t)BB * NN;                 // 16384
    unsigned* wrow  = (unsigned*)d_ws;                 // 16384
    unsigned* wcol  = wrow + NQ;                       // 16384
    unsigned* wcov  = wcol + NQ;                       // 8192
    unsigned* wkeys = wcov + (size_t)BB * MP;

    // 16-chunk path: wkeys 16*16 u32/query + wkeys2 4*16 u32/query + partials
    size_t need16 = ((size_t)(NQ * 2 + BB * MP) + NQ * 16 * 16 + NQ * 4 * 16 + 512) * 4;

    hipMemsetAsync(wrow, 0xFF, (NQ * 2 + (size_t)BB * MP) * sizeof(unsigned), stream);

    if (ws_size >= need16) {
        unsigned* wkeys2 = wkeys + NQ * 16 * 16;
        float* partials  = (float*)(wkeys2 + NQ * 4 * 16);
        kfused<16><<<2304, 256, 0, stream>>>(pred, gt, partial, wrow, wcol, wcov, wkeys);
        kmergeA<16><<<256, 256, 0, stream>>>(wkeys, wkeys2);
        kmergeB<4><<<256, 64, 0, stream>>>(pred, wkeys2, partials);
        kfinal<<<1, 1024, 0, stream>>>(wrow, wcol, wcov, partials, partial, out);
    } else {
        // fallback: proven 8-chunk geometry (~10.6 MB)
        float* partials = (float*)(wkeys + NQ * 8 * 16);
        kfused<8><<<1152, 256, 0, stream>>>(pred, gt, partial, wrow, wcol, wcov, wkeys);
        kmergeB<8><<<256, 64, 0, stream>>>(pred, wkeys, partials);
        kfinal<<<1, 1024, 0, stream>>>(wrow, wcol, wcov, partials, partial, out);
    }
}